// Round 3
// baseline (2383.356 us; speedup 1.0000x reference)
//
#include <hip/hip_runtime.h>

// Transformer block + switch-MoE, MI355X gfx950. ALL I/O IS FLOAT32 (per the
// harness contract: dtypes follow the reference, which is pure f32).
// R2 root-cause: rounds 0/1 read f32 buffers as bf16 -> garbage exponents ->
// inf/NaN through softmax. This round is the f32-correct rewrite:
//  - QKV / out-proj GEMMs: split A and W into 3 bf16 limbs, 6 MFMA passes
//    (limbs (0,0),(0,1),(1,0),(1,1),(0,2),(2,0)) -> rel err ~2^-25 (exact-grade,
//    protects the discrete router argmax + capacity scan)
//  - scores/softmax/PV: f32 vector flash attention (online softmax)
//  - LN / router logits / argmax / ballot capacity scan: f32 / exact integer
//  - expert FFN: f32 vector (tiny FLOPs)
// Scratch: d_out is 96 MiB of f32 -> hosts qbuf/kbuf/vbuf; flash writes Z
// in-place over Q (safe: Q tile staged to LDS before first barrier, Z stored
// after last; regions are block-unique). ws peak use = 54 MiB.

typedef __bf16 bf16;
typedef __bf16 bf16x4 __attribute__((ext_vector_type(4)));
typedef __bf16 bf16x8 __attribute__((ext_vector_type(8)));
typedef float  f32x4  __attribute__((ext_vector_type(4)));

#define NB    8
#define LL    1024
#define CC    1024
#define NH    16
#define DKD   64
#define NE    16
#define NHID  64
#define CAP   256
#define NTOK  (NB*LL)          // 8192
#define MB    (1024*1024)

// ---------------- split f32 -> 3 bf16 limbs (hi, mid, lo) --------------------
__global__ __launch_bounds__(256)
void split3(const float* __restrict__ z, bf16* __restrict__ z1,
            bf16* __restrict__ z2, bf16* __restrict__ z3)
{
    const size_t i = ((size_t)blockIdx.x * 256 + threadIdx.x) * 4;
    const f32x4 v = *(const f32x4*)(z + i);
    bf16x4 a, b, c;
#pragma unroll
    for (int k = 0; k < 4; k++) {
        const float x  = v[k];
        const bf16  hi = (bf16)x;
        const float r1 = x - (float)hi;
        const bf16  md = (bf16)r1;
        const float r2 = r1 - (float)md;
        a[k] = hi; b[k] = md; c[k] = (bf16)r2;
    }
    *(bf16x4*)(z1 + i) = a;
    *(bf16x4*)(z2 + i) = b;
    *(bf16x4*)(z3 + i) = c;
}

// ------- GEMM: C[M,N] = A[M,K] @ W[N,K]^T + bias, A/W as 3 bf16 limbs -------
// 16x16x32 bf16 MFMA, block 128x128 (4 waves, wave = 64x64).
// C/D layout: col=lane&15, row=(lane>>4)*4+reg (m89-verified).
__global__ __launch_bounds__(256)
void gemm_limb6(const bf16* __restrict__ A0, const bf16* __restrict__ A1,
                const bf16* __restrict__ A2,
                const bf16* __restrict__ W0, const bf16* __restrict__ W1l,
                const bf16* __restrict__ W2l,
                const float* __restrict__ bias, float* __restrict__ C,
                int M, int N, int K)
{
    const int tid  = threadIdx.x;
    const int lane = tid & 63;
    const int wv   = tid >> 6;
    const int bm = blockIdx.x * 128 + (wv & 1) * 64;
    const int bn = blockIdx.y * 128 + (wv >> 1) * 64;
    const int lr = lane & 15;
    const int lq = lane >> 4;

    f32x4 acc[4][4];
#pragma unroll
    for (int i = 0; i < 4; i++)
#pragma unroll
        for (int j = 0; j < 4; j++) acc[i][j] = f32x4{0.f, 0.f, 0.f, 0.f};

    for (int k0 = 0; k0 < K; k0 += 32) {
        bf16x8 af[3][4], bfr[3][4];
#pragma unroll
        for (int i = 0; i < 4; i++) {
            const size_t off = (size_t)(bm + i * 16 + lr) * K + k0 + lq * 8;
            af[0][i] = *(const bf16x8*)(A0 + off);
            af[1][i] = *(const bf16x8*)(A1 + off);
            af[2][i] = *(const bf16x8*)(A2 + off);
        }
#pragma unroll
        for (int j = 0; j < 4; j++) {
            const size_t off = (size_t)(bn + j * 16 + lr) * K + k0 + lq * 8;
            bfr[0][j] = *(const bf16x8*)(W0 + off);
            bfr[1][j] = *(const bf16x8*)(W1l + off);
            bfr[2][j] = *(const bf16x8*)(W2l + off);
        }
        constexpr int PI[6] = {0, 0, 1, 1, 0, 2};
        constexpr int PJ[6] = {0, 1, 0, 1, 2, 0};
#pragma unroll
        for (int p = 0; p < 6; p++)
#pragma unroll
            for (int i = 0; i < 4; i++)
#pragma unroll
                for (int j = 0; j < 4; j++)
                    acc[i][j] = __builtin_amdgcn_mfma_f32_16x16x32_bf16(
                        af[PI[p]][i], bfr[PJ[p]][j], acc[i][j], 0, 0, 0);
    }
#pragma unroll
    for (int i = 0; i < 4; i++)
#pragma unroll
        for (int j = 0; j < 4; j++) {
            const int col = bn + j * 16 + lr;
            const float bv = bias[col];
#pragma unroll
            for (int r = 0; r < 4; r++) {
                const int row = bm + i * 16 + lq * 4 + r;
                C[(size_t)row * N + col] = acc[i][j][r] + bv;
            }
        }
}

// ---------------- flash attention, f32 vector, online softmax ----------------
// grid (L/64, H, B), block 256. Q/K/V f32 [B*L, H*DK] row-major. Z may alias Q
// (per-block region; Q staged to LDS before first barrier, Z stored at end).
__global__ __launch_bounds__(256)
void flash_f32(const float* __restrict__ Q, const float* __restrict__ Kb,
               const float* __restrict__ Vb, float* __restrict__ Z)
{
    __shared__ float Qs[64][68];
    __shared__ float Ks[64][68];
    __shared__ float Vs[64][68];

    const int tid = threadIdx.x;
    const int b = blockIdx.z, h = blockIdx.y, q0 = blockIdx.x * 64;
    const size_t base = (size_t)b * LL * 1024 + (size_t)h * 64;

#pragma unroll
    for (int p = 0; p < 4; p++) {               // stage Q tile (pre-scaled by 1/8)
        const int idx = p * 256 + tid;
        const int rr = idx >> 4, dq = idx & 15;
        f32x4 v = *(const f32x4*)(Q + base + (size_t)(q0 + rr) * 1024 + dq * 4);
        v *= 0.125f;
        *(f32x4*)&Qs[rr][dq * 4] = v;
    }

    const int r  = tid >> 2;
    const int cq = tid & 3;
    const int c0 = cq * 16;
    const int lanebase = (tid & 63) & ~3;

    float m_r = -3.0e38f, l_r = 0.f;
    f32x4 o4[4];
#pragma unroll
    for (int g = 0; g < 4; g++) o4[g] = f32x4{0.f, 0.f, 0.f, 0.f};

    for (int kt = 0; kt < LL / 64; kt++) {
        __syncthreads();
        const int k0 = kt * 64;
#pragma unroll
        for (int p = 0; p < 4; p++) {           // stage K,V tiles
            const int idx = p * 256 + tid;
            const int rr = idx >> 4, dq = idx & 15;
            *(f32x4*)&Ks[rr][dq * 4] =
                *(const f32x4*)(Kb + base + (size_t)(k0 + rr) * 1024 + dq * 4);
            *(f32x4*)&Vs[rr][dq * 4] =
                *(const f32x4*)(Vb + base + (size_t)(k0 + rr) * 1024 + dq * 4);
        }
        __syncthreads();

        float s[16];
#pragma unroll
        for (int j = 0; j < 16; j++) s[j] = 0.f;
        for (int dg = 0; dg < 16; dg++) {
            const f32x4 q4 = *(const f32x4*)&Qs[r][dg * 4];
#pragma unroll
            for (int j = 0; j < 16; j++) {
                const f32x4 k4 = *(const f32x4*)&Ks[cq + 4 * j][dg * 4];
                s[j] += q4[0]*k4[0] + q4[1]*k4[1] + q4[2]*k4[2] + q4[3]*k4[3];
            }
        }
        float tmax = s[0];
#pragma unroll
        for (int j = 1; j < 16; j++) tmax = fmaxf(tmax, s[j]);
        tmax = fmaxf(tmax, __shfl_xor(tmax, 1));
        tmax = fmaxf(tmax, __shfl_xor(tmax, 2));
        const float mnew = fmaxf(m_r, tmax);
        const float alpha = expf(m_r - mnew);

        float p_[16];
        float psum = 0.f;
#pragma unroll
        for (int j = 0; j < 16; j++) { p_[j] = expf(s[j] - mnew); psum += p_[j]; }
        psum += __shfl_xor(psum, 1);
        psum += __shfl_xor(psum, 2);
        l_r = l_r * alpha + psum;
        m_r = mnew;
#pragma unroll
        for (int g = 0; g < 4; g++) o4[g] *= alpha;

#pragma unroll
        for (int j = 0; j < 16; j++) {
#pragma unroll
            for (int c2 = 0; c2 < 4; c2++) {
                const float pv = __shfl(p_[j], lanebase + c2, 64);
                const int k = c2 + 4 * j;
                const float* vrow = &Vs[k][c0];
#pragma unroll
                for (int g = 0; g < 4; g++) {
                    const f32x4 v4 = *(const f32x4*)(vrow + g * 4);
                    o4[g] += pv * v4;
                }
            }
        }
    }
    const float inv = 1.f / l_r;
    const size_t zoff = ((size_t)b * LL + q0 + r) * 1024 + h * 64 + c0;
#pragma unroll
    for (int g = 0; g < 4; g++) {
        f32x4 ov = o4[g] * inv;
        *(f32x4*)(Z + zoff + g * 4) = ov;
    }
}

// ---------------- LayerNorm(qx + att) ----------------------------------------
__global__ __launch_bounds__(256)
void ln_kernel(const float* __restrict__ qx, const float* __restrict__ att,
               const float* __restrict__ w, const float* __restrict__ bch,
               float* __restrict__ zn)
{
    const int row = blockIdx.x, tid = threadIdx.x;
    const size_t off = (size_t)row * 1024 + tid * 4;
    const f32x4 q4 = *(const f32x4*)(qx + off);
    const f32x4 a4 = *(const f32x4*)(att + off);
    float x[4];
#pragma unroll
    for (int i = 0; i < 4; i++) x[i] = q4[i] + a4[i];

    __shared__ float red[8];
    float part = x[0] + x[1] + x[2] + x[3];
#pragma unroll
    for (int d = 1; d < 64; d <<= 1) part += __shfl_xor(part, d);
    if ((tid & 63) == 0) red[tid >> 6] = part;
    __syncthreads();
    const float mu = (red[0] + red[1] + red[2] + red[3]) * (1.f / 1024.f);

    float p2 = 0.f;
#pragma unroll
    for (int i = 0; i < 4; i++) { const float d = x[i] - mu; p2 += d * d; }
#pragma unroll
    for (int d = 1; d < 64; d <<= 1) p2 += __shfl_xor(p2, d);
    if ((tid & 63) == 0) red[4 + (tid >> 6)] = p2;
    __syncthreads();
    const float var  = (red[4] + red[5] + red[6] + red[7]) * (1.f / 1024.f);
    const float rstd = 1.f / sqrtf(var + 1e-5f);

    const f32x4 w4 = *(const f32x4*)(w + tid * 4);
    const f32x4 b4 = *(const f32x4*)(bch + tid * 4);
    f32x4 out;
#pragma unroll
    for (int i = 0; i < 4; i++)
        out[i] = (x[i] - mu) * rstd * w4[i] + b4[i];
    *(f32x4*)(zn + off) = out;
}

// ---------------- router: logits + first-max argmax --------------------------
__global__ __launch_bounds__(64)
void router_kernel(const float* __restrict__ zn, const float* __restrict__ Wsw,
                   const float* __restrict__ bsw, int* __restrict__ routes)
{
    const int t = blockIdx.x, lane = threadIdx.x;
    const float* x = zn + (size_t)t * 1024;
    float acc[16];
#pragma unroll
    for (int e = 0; e < 16; e++) acc[e] = 0.f;
    for (int ii = 0; ii < 16; ii++) {
        const float xv = x[lane + 64 * ii];
#pragma unroll
        for (int e = 0; e < 16; e++)
            acc[e] += xv * Wsw[e * 1024 + lane + 64 * ii];
    }
#pragma unroll
    for (int e = 0; e < 16; e++)
#pragma unroll
        for (int d = 1; d < 64; d <<= 1) acc[e] += __shfl_xor(acc[e], d);
    if (lane == 0) {
        float best = acc[0] + bsw[0];
        int bi = 0;
#pragma unroll
        for (int e = 1; e < 16; e++) {
            const float lg = acc[e] + bsw[e];
            if (lg > best) { best = lg; bi = e; }   // strict > == np first-max
        }
        routes[t] = bi;
    }
}

// ---------------- capacity scan: wave e ballots over tokens ------------------
__global__ __launch_bounds__(1024)
void route_scan(const int* __restrict__ routes, int* __restrict__ slot_of_token,
                int* __restrict__ token_of_slot)
{
    const int wv = threadIdx.x >> 6;      // expert id
    const int lane = threadIdx.x & 63;
    int cnt = 0;
    for (int c = 0; c < NTOK / 64; c++) {
        const int tok = c * 64 + lane;
        const bool match = (routes[tok] == wv);
        const unsigned long long mask = __ballot(match);
        const int pos = cnt + __popcll(mask & ((1ull << lane) - 1ull));
        if (match) {
            if (pos < CAP) {
                slot_of_token[tok] = wv * CAP + pos;
                token_of_slot[wv * CAP + pos] = tok;
            } else slot_of_token[tok] = -1;
        }
        cnt += __popcll(mask);
    }
    const int filled = cnt < CAP ? cnt : CAP;
    for (int s2 = filled + lane; s2 < CAP; s2 += 64)
        token_of_slot[wv * CAP + s2] = -1;   // unfilled slots never gathered
}

// ---------------- expert FFN (f32 weights) -----------------------------------
__global__ __launch_bounds__(64)
void ffn1(const float* __restrict__ zn, const int* __restrict__ token_of_slot,
          const float* __restrict__ W1, const float* __restrict__ b1,
          float* __restrict__ hbuf)
{
    const int s = blockIdx.x, lane = threadIdx.x;
    const int tok = token_of_slot[s];
    if (tok < 0) return;
    const int e = s >> 8;
    const float* w = W1 + (size_t)e * CC * NHID + lane;
    const float* x = zn + (size_t)tok * 1024;
    float acc = 0.f;
#pragma unroll 8
    for (int i = 0; i < 1024; i++) acc += x[i] * w[(size_t)i * NHID];
    acc += b1[e * NHID + lane];
    hbuf[(size_t)s * NHID + lane] = fmaxf(acc, 0.f);
}

__global__ __launch_bounds__(256)
void ffn2(const float* __restrict__ hbuf, const int* __restrict__ token_of_slot,
          const float* __restrict__ W2, const float* __restrict__ b2,
          float* __restrict__ ybuf)
{
    const int s = blockIdx.x, tid = threadIdx.x;
    const int tok = token_of_slot[s];
    if (tok < 0) return;
    const int e = s >> 8;
    const int c0 = tid * 4;
    const float* w = W2 + (size_t)e * NHID * CC + c0;
    const float* hrow = hbuf + (size_t)s * NHID;
    const f32x4 b4 = *(const f32x4*)(b2 + e * CC + c0);
    float a0 = b4[0], a1 = b4[1], a2 = b4[2], a3 = b4[3];
#pragma unroll 8
    for (int k = 0; k < NHID; k++) {
        const float hv = hrow[k];
        const f32x4 w4 = *(const f32x4*)(w + (size_t)k * CC);
        a0 += hv * w4[0]; a1 += hv * w4[1];
        a2 += hv * w4[2]; a3 += hv * w4[3];
    }
    const f32x4 out = {a0, a1, a2, a3};
    *(f32x4*)(ybuf + (size_t)s * 1024 + c0) = out;
}

// ---------------- final: out = zn + (kept ? y : zn) --------------------------
__global__ __launch_bounds__(256)
void assemble(const float* __restrict__ zn, const float* __restrict__ ybuf,
              const int* __restrict__ slot_of_token, float* __restrict__ out)
{
    const int tok = blockIdx.x, tid = threadIdx.x;
    const int slot = slot_of_token[tok];
    const size_t off = (size_t)tok * 1024 + tid * 4;
    const f32x4 z4 = *(const f32x4*)(zn + off);
    f32x4 m4;
    if (slot >= 0) m4 = *(const f32x4*)(ybuf + (size_t)slot * 1024 + tid * 4);
    else           m4 = z4;                 // dropped token passes through
    f32x4 o;
#pragma unroll
    for (int i = 0; i < 4; i++) o[i] = z4[i] + m4[i];
    *(f32x4*)(out + off) = o;
}

__global__ __launch_bounds__(256)
void fill_mask(float* __restrict__ p, int n)
{
    const int i = blockIdx.x * 256 + threadIdx.x;
    if (i < n) p[i] = 1.0f;
}

// ---------------- launch -----------------------------------------------------
extern "C" void kernel_launch(void* const* d_in, const int* in_sizes, int n_in,
                              void* d_out, int out_size, void* d_ws, size_t ws_size,
                              hipStream_t stream)
{
    (void)out_size; (void)ws_size;
    const float* qx = (const float*)d_in[0];
    const float* kx = (const float*)d_in[1];
    const float* vx = (const float*)d_in[2];
    // maskPAD (bool[8192]) may or may not occupy slot 3.
    int wbase = 4;
    if (n_in >= 4 && in_sizes[3] != NB * LL) wbase = 3;
    const float* WQ   = (const float*)d_in[wbase + 0];
    const float* bQ   = (const float*)d_in[wbase + 1];
    const float* WK   = (const float*)d_in[wbase + 2];
    const float* bK   = (const float*)d_in[wbase + 3];
    const float* WV   = (const float*)d_in[wbase + 4];
    const float* bV   = (const float*)d_in[wbase + 5];
    const float* WO   = (const float*)d_in[wbase + 6];
    const float* bO   = (const float*)d_in[wbase + 7];
    const float* ln1w = (const float*)d_in[wbase + 8];
    const float* ln1b = (const float*)d_in[wbase + 9];
    const float* Wsw  = (const float*)d_in[wbase + 10];
    const float* bsw  = (const float*)d_in[wbase + 11];
    const float* W1   = (const float*)d_in[wbase + 12];
    const float* b1   = (const float*)d_in[wbase + 13];
    const float* W2   = (const float*)d_in[wbase + 14];
    const float* b2   = (const float*)d_in[wbase + 15];

    // d_out (f32): out0 [0,32M) | kx copy [32M,64M) | vx copy [64M,96M) | mask
    char* D = (char*)d_out;
    float* qbuf = (float*)(D + (size_t) 0 * MB);
    float* kbuf = (float*)(D + (size_t)32 * MB);
    float* vbuf = (float*)(D + (size_t)64 * MB);
    float* zbuf   = qbuf;   // flash writes Z in-place over Q (block-unique regions)
    float* attbuf = qbuf;   // out-proj output over dead z (z consumed by split3)

    // ws layout (peak 54 MiB):
    char* wsb = (char*)d_ws;
    bf16* la0 = (bf16*)(wsb + (size_t) 0 * MB);   // A limbs (8M elems x 2B)
    bf16* la1 = (bf16*)(wsb + (size_t)16 * MB);
    bf16* la2 = (bf16*)(wsb + (size_t)32 * MB);
    bf16* lw0 = (bf16*)(wsb + (size_t)48 * MB);   // W limbs (1M elems x 2B)
    bf16* lw1 = (bf16*)(wsb + (size_t)50 * MB);
    bf16* lw2 = (bf16*)(wsb + (size_t)52 * MB);
    float* znbuf = (float*)(wsb + (size_t)0 * MB);        // over dead la0/la1
    float* ybuf  = (float*)(wsb + (size_t)32 * MB);       // over dead la2
    int* routes        = (int*)(wsb + (size_t)48 * MB);             // over dead lw0
    int* slot_of_token = (int*)(wsb + (size_t)48 * MB + 64 * 1024);
    int* token_of_slot = (int*)(wsb + (size_t)48 * MB + 128 * 1024);
    float* hbuf        = (float*)(wsb + (size_t)49 * MB);           // over dead lw0/lw1

    const dim3 gblk(NTOK / 128, CC / 128, 1);
    const int GA = NTOK * 1024 / (256 * 4);   // 8192 blocks: split 8M elems
    const int GW = CC * 1024 / (256 * 4);     // 1024 blocks: split 1M elems

    // Q = qx @ WQ^T + bQ  (limb-split GEMM), same for K, V
    split3<<<GA, 256, 0, stream>>>(qx, la0, la1, la2);
    split3<<<GW, 256, 0, stream>>>(WQ, lw0, lw1, lw2);
    gemm_limb6<<<gblk, 256, 0, stream>>>(la0, la1, la2, lw0, lw1, lw2, bQ, qbuf, NTOK, CC, CC);
    split3<<<GA, 256, 0, stream>>>(kx, la0, la1, la2);
    split3<<<GW, 256, 0, stream>>>(WK, lw0, lw1, lw2);
    gemm_limb6<<<gblk, 256, 0, stream>>>(la0, la1, la2, lw0, lw1, lw2, bK, kbuf, NTOK, CC, CC);
    split3<<<GA, 256, 0, stream>>>(vx, la0, la1, la2);
    split3<<<GW, 256, 0, stream>>>(WV, lw0, lw1, lw2);
    gemm_limb6<<<gblk, 256, 0, stream>>>(la0, la1, la2, lw0, lw1, lw2, bV, vbuf, NTOK, CC, CC);

    flash_f32<<<dim3(LL / 64, NH, NB), 256, 0, stream>>>(qbuf, kbuf, vbuf, zbuf);

    // att = z @ WO^T + bO
    split3<<<GA, 256, 0, stream>>>(zbuf, la0, la1, la2);
    split3<<<GW, 256, 0, stream>>>(WO, lw0, lw1, lw2);
    gemm_limb6<<<gblk, 256, 0, stream>>>(la0, la1, la2, lw0, lw1, lw2, bO, attbuf, NTOK, CC, CC);

    ln_kernel<<<NTOK, 256, 0, stream>>>(qx, attbuf, ln1w, ln1b, znbuf);

    router_kernel<<<NTOK, 64, 0, stream>>>(znbuf, Wsw, bsw, routes);
    route_scan<<<1, 1024, 0, stream>>>(routes, slot_of_token, token_of_slot);

    ffn1<<<NE * CAP, 64, 0, stream>>>(znbuf, token_of_slot, W1, b1, hbuf);
    ffn2<<<NE * CAP, 256, 0, stream>>>(hbuf, token_of_slot, W2, b2, ybuf);

    assemble<<<NTOK, 256, 0, stream>>>(znbuf, ybuf, slot_of_token, (float*)d_out);

    // passthrough outputs: kx, vx copies (overwrite dead kbuf/vbuf), mask = 1.0f
    hipMemcpyAsync(D + (size_t)32 * MB, (const void*)kx,
                   (size_t)NTOK * 1024 * 4, hipMemcpyDeviceToDevice, stream);
    hipMemcpyAsync(D + (size_t)64 * MB, (const void*)vx,
                   (size_t)NTOK * 1024 * 4, hipMemcpyDeviceToDevice, stream);
    fill_mask<<<NTOK / 256, 256, 0, stream>>>((float*)d_out + (size_t)3 * NTOK * 1024, NTOK);
}

// Round 4
// 1520.918 us; speedup vs baseline: 1.5671x; 1.5671x over previous
//
#include <hip/hip_runtime.h>

// Transformer block + switch-MoE, MI355X gfx950. ALL I/O FLOAT32.
// R4: flash attention moved to bf16-limb MFMA (16x16x32, layouts identical to
// the R3-verified GEMM). Scores and PV use the 6-pass 3-limb product set
// (rel err ~2^-24) so the discrete router argmax/capacity scan is preserved.
// Z is written in-place over the Q f32 buffer (byte-identical element map,
// block-exclusive regions). GEMMs unchanged from R3 (verified).

typedef __bf16 bf16;
typedef __bf16 bf16x4 __attribute__((ext_vector_type(4)));
typedef __bf16 bf16x8 __attribute__((ext_vector_type(8)));
typedef float  f32x4  __attribute__((ext_vector_type(4)));

#define NB    8
#define LL    1024
#define CC    1024
#define NH    16
#define DKD   64
#define NE    16
#define NHID  64
#define CAP   256
#define NTOK  (NB*LL)          // 8192
#define MB    (1024*1024)

__device__ inline void split3v(const f32x4 v, bf16x4& a, bf16x4& b, bf16x4& c)
{
#pragma unroll
    for (int k = 0; k < 4; k++) {
        const float x  = v[k];
        const bf16  hi = (bf16)x;
        const float r1 = x - (float)hi;
        const bf16  md = (bf16)r1;
        const float r2 = r1 - (float)md;
        a[k] = hi; b[k] = md; c[k] = (bf16)r2;
    }
}

__device__ inline bf16x8 pack8(const bf16x4 a, const bf16x4 b)
{
    bf16x8 r;
#pragma unroll
    for (int e = 0; e < 4; e++) { r[e] = a[e]; r[4 + e] = b[e]; }
    return r;
}

// ---------------- split f32 -> 3 bf16 limbs (hi, mid, lo) --------------------
__global__ __launch_bounds__(256)
void split3(const float* __restrict__ z, bf16* __restrict__ z1,
            bf16* __restrict__ z2, bf16* __restrict__ z3)
{
    const size_t i = ((size_t)blockIdx.x * 256 + threadIdx.x) * 4;
    const f32x4 v = *(const f32x4*)(z + i);
    bf16x4 a, b, c;
    split3v(v, a, b, c);
    *(bf16x4*)(z1 + i) = a;
    *(bf16x4*)(z2 + i) = b;
    *(bf16x4*)(z3 + i) = c;
}

// ------- GEMM: C[M,N] = A[M,K] @ W[N,K]^T + bias, A/W as 3 bf16 limbs -------
// (unchanged from R3 -- verified)
__global__ __launch_bounds__(256)
void gemm_limb6(const bf16* __restrict__ A0, const bf16* __restrict__ A1,
                const bf16* __restrict__ A2,
                const bf16* __restrict__ W0, const bf16* __restrict__ W1l,
                const bf16* __restrict__ W2l,
                const float* __restrict__ bias, float* __restrict__ C,
                int M, int N, int K)
{
    const int tid  = threadIdx.x;
    const int lane = tid & 63;
    const int wv   = tid >> 6;
    const int bm = blockIdx.x * 128 + (wv & 1) * 64;
    const int bn = blockIdx.y * 128 + (wv >> 1) * 64;
    const int lr = lane & 15;
    const int lq = lane >> 4;

    f32x4 acc[4][4];
#pragma unroll
    for (int i = 0; i < 4; i++)
#pragma unroll
        for (int j = 0; j < 4; j++) acc[i][j] = f32x4{0.f, 0.f, 0.f, 0.f};

    for (int k0 = 0; k0 < K; k0 += 32) {
        bf16x8 af[3][4], bfr[3][4];
#pragma unroll
        for (int i = 0; i < 4; i++) {
            const size_t off = (size_t)(bm + i * 16 + lr) * K + k0 + lq * 8;
            af[0][i] = *(const bf16x8*)(A0 + off);
            af[1][i] = *(const bf16x8*)(A1 + off);
            af[2][i] = *(const bf16x8*)(A2 + off);
        }
#pragma unroll
        for (int j = 0; j < 4; j++) {
            const size_t off = (size_t)(bn + j * 16 + lr) * K + k0 + lq * 8;
            bfr[0][j] = *(const bf16x8*)(W0 + off);
            bfr[1][j] = *(const bf16x8*)(W1l + off);
            bfr[2][j] = *(const bf16x8*)(W2l + off);
        }
        constexpr int PI[6] = {0, 0, 1, 1, 0, 2};
        constexpr int PJ[6] = {0, 1, 0, 1, 2, 0};
#pragma unroll
        for (int p = 0; p < 6; p++)
#pragma unroll
            for (int i = 0; i < 4; i++)
#pragma unroll
                for (int j = 0; j < 4; j++)
                    acc[i][j] = __builtin_amdgcn_mfma_f32_16x16x32_bf16(
                        af[PI[p]][i], bfr[PJ[p]][j], acc[i][j], 0, 0, 0);
    }
#pragma unroll
    for (int i = 0; i < 4; i++)
#pragma unroll
        for (int j = 0; j < 4; j++) {
            const int col = bn + j * 16 + lr;
            const float bv = bias[col];
#pragma unroll
            for (int r = 0; r < 4; r++) {
                const int row = bm + i * 16 + lq * 4 + r;
                C[(size_t)row * N + col] = acc[i][j][r] + bv;
            }
        }
}

// ---------------- flash attention, bf16-limb MFMA, online softmax ------------
// grid 1024 (XCD-swizzled), block 256 = 4 waves; wave = 32 q-rows; k-tile 32.
// Qf is read as Q and overwritten with Z (identical element map, block-excl).
__global__ __launch_bounds__(256)
void flash_mfma(float* __restrict__ Qf, const float* __restrict__ Kf,
                const float* __restrict__ Vf)
{
    __shared__ bf16 Ks[3][32][72];     // [limb][ktok][d]   (pad 72 -> 2-way free)
    __shared__ bf16 Vs[3][64][40];     // [limb][d][ktok]   (transposed)
    __shared__ float Ps[128][36];      // P round-trip, wave-private rows

    const int tid  = threadIdx.x;
    const int lane = tid & 63;
    const int w    = tid >> 6;
    const int lr   = lane & 15;
    const int lq   = lane >> 4;

    // XCD-locality swizzle (perf heuristic only): bh groups pinned per bid%8
    const int bid = (int)blockIdx.x;
    const int qb  = (bid >> 3) & 7;
    const int bh  = (bid & 7) * 16 + (bid >> 6);
    const int b   = bh >> 4, h = bh & 15;
    const int q0  = qb * 128;
    const size_t base = (size_t)b * LL * 1024 + (size_t)h * 64;

    // ---- Q fragments: 3 limbs x 2 mi x 2 ks, pre-scaled by 1/8 (exact) ----
    bf16x8 qf[3][2][2];
#pragma unroll
    for (int mi = 0; mi < 2; mi++)
#pragma unroll
        for (int ks = 0; ks < 2; ks++) {
            const float* src = Qf + base +
                (size_t)(q0 + w * 32 + mi * 16 + lr) * 1024 + ks * 32 + lq * 8;
            f32x4 v0 = *(const f32x4*)src;
            f32x4 v1 = *(const f32x4*)(src + 4);
            v0 *= 0.125f; v1 *= 0.125f;
            bf16x4 a0, b0, c0, a1, b1, c1;
            split3v(v0, a0, b0, c0);
            split3v(v1, a1, b1, c1);
            qf[0][mi][ks] = pack8(a0, a1);
            qf[1][mi][ks] = pack8(b0, b1);
            qf[2][mi][ks] = pack8(c0, c1);
        }

    float m_[2][4], l_[2][4];
    f32x4 accO[2][4];
#pragma unroll
    for (int mi = 0; mi < 2; mi++)
#pragma unroll
        for (int rr = 0; rr < 4; rr++) { m_[mi][rr] = -3.0e38f; l_[mi][rr] = 0.f; }
#pragma unroll
    for (int mi = 0; mi < 2; mi++)
#pragma unroll
        for (int nd = 0; nd < 4; nd++) accO[mi][nd] = f32x4{0.f, 0.f, 0.f, 0.f};

    constexpr int PI[6] = {0, 0, 1, 1, 0, 2};
    constexpr int PJ[6] = {0, 1, 0, 1, 2, 0};

    for (int kt = 0; kt < 32; kt++) {
        const int k0 = kt * 32;
        __syncthreads();
        // ---- stage K (row-major) and V (transposed) with in-LDS limb split --
#pragma unroll
        for (int it = 0; it < 2; it++) {
            const int c = tid & 15;               // d-chunk of 4
            const int r = (tid >> 4) + it * 16;   // ktok 0..31
            const size_t g = base + (size_t)(k0 + r) * 1024 + c * 4;
            {
                const f32x4 kv = *(const f32x4*)(Kf + g);
                bf16x4 a, bq, cq; split3v(kv, a, bq, cq);
                *(bf16x4*)&Ks[0][r][c * 4] = a;
                *(bf16x4*)&Ks[1][r][c * 4] = bq;
                *(bf16x4*)&Ks[2][r][c * 4] = cq;
            }
            {
                const f32x4 vv = *(const f32x4*)(Vf + g);
                bf16x4 a, bq, cq; split3v(vv, a, bq, cq);
#pragma unroll
                for (int i2 = 0; i2 < 4; i2++) {
                    Vs[0][c * 4 + i2][r] = a[i2];
                    Vs[1][c * 4 + i2][r] = bq[i2];
                    Vs[2][c * 4 + i2][r] = cq[i2];
                }
            }
        }
        __syncthreads();

        // ---- scores: accS[mi][nj], 48 MFMA ----
        f32x4 accS[2][2];
#pragma unroll
        for (int mi = 0; mi < 2; mi++)
#pragma unroll
            for (int nj = 0; nj < 2; nj++) accS[mi][nj] = f32x4{0.f, 0.f, 0.f, 0.f};
#pragma unroll
        for (int nj = 0; nj < 2; nj++) {
            bf16x8 kfr[3][2];
#pragma unroll
            for (int ks = 0; ks < 2; ks++) {
                kfr[0][ks] = *(const bf16x8*)&Ks[0][nj * 16 + lr][ks * 32 + lq * 8];
                kfr[1][ks] = *(const bf16x8*)&Ks[1][nj * 16 + lr][ks * 32 + lq * 8];
                kfr[2][ks] = *(const bf16x8*)&Ks[2][nj * 16 + lr][ks * 32 + lq * 8];
            }
#pragma unroll
            for (int p = 0; p < 6; p++)
#pragma unroll
                for (int mi = 0; mi < 2; mi++)
#pragma unroll
                    for (int ks = 0; ks < 2; ks++)
                        accS[mi][nj] = __builtin_amdgcn_mfma_f32_16x16x32_bf16(
                            qf[PI[p]][mi][ks], kfr[PJ[p]][ks], accS[mi][nj], 0, 0, 0);
        }

        // ---- online softmax (rows live on 16-lane groups) ----
#pragma unroll
        for (int mi = 0; mi < 2; mi++)
#pragma unroll
            for (int rr = 0; rr < 4; rr++) {
                const float s0 = accS[mi][0][rr], s1 = accS[mi][1][rr];
                float t = fmaxf(s0, s1);
                t = fmaxf(t, __shfl_xor(t, 1));
                t = fmaxf(t, __shfl_xor(t, 2));
                t = fmaxf(t, __shfl_xor(t, 4));
                t = fmaxf(t, __shfl_xor(t, 8));
                const float mnew  = fmaxf(m_[mi][rr], t);
                const float alpha = expf(m_[mi][rr] - mnew);
                const float p0 = expf(s0 - mnew);
                const float p1 = expf(s1 - mnew);
                float ps = p0 + p1;
                ps += __shfl_xor(ps, 1);
                ps += __shfl_xor(ps, 2);
                ps += __shfl_xor(ps, 4);
                ps += __shfl_xor(ps, 8);
                l_[mi][rr] = l_[mi][rr] * alpha + ps;
                m_[mi][rr] = mnew;
                const int prow = w * 32 + mi * 16 + lq * 4 + rr;
                Ps[prow][lr]      = p0;
                Ps[prow][16 + lr] = p1;
#pragma unroll
                for (int nd = 0; nd < 4; nd++) accO[mi][nd][rr] *= alpha;
            }

        // ---- P: C-layout -> A-layout via LDS (same-wave, in-order DS) ----
        bf16x8 pf[3][2];
#pragma unroll
        for (int mi = 0; mi < 2; mi++) {
            const float* pr = &Ps[w * 32 + mi * 16 + lr][lq * 8];
            const f32x4 v0 = *(const f32x4*)pr;
            const f32x4 v1 = *(const f32x4*)(pr + 4);
            bf16x4 a0, b0, c0, a1, b1, c1;
            split3v(v0, a0, b0, c0);
            split3v(v1, a1, b1, c1);
            pf[0][mi] = pack8(a0, a1);
            pf[1][mi] = pack8(b0, b1);
            pf[2][mi] = pack8(c0, c1);
        }

        // ---- PV: accO += P*V, 48 MFMA ----
#pragma unroll
        for (int nd = 0; nd < 4; nd++) {
            bf16x8 vfr[3];
            vfr[0] = *(const bf16x8*)&Vs[0][nd * 16 + lr][lq * 8];
            vfr[1] = *(const bf16x8*)&Vs[1][nd * 16 + lr][lq * 8];
            vfr[2] = *(const bf16x8*)&Vs[2][nd * 16 + lr][lq * 8];
#pragma unroll
            for (int p = 0; p < 6; p++)
#pragma unroll
                for (int mi = 0; mi < 2; mi++)
                    accO[mi][nd] = __builtin_amdgcn_mfma_f32_16x16x32_bf16(
                        pf[PI[p]][mi], vfr[PJ[p]], accO[mi][nd], 0, 0, 0);
        }
    }

    // ---- epilogue: Z = accO / l, in-place over Qf ----
#pragma unroll
    for (int mi = 0; mi < 2; mi++) {
        float inv[4];
#pragma unroll
        for (int rr = 0; rr < 4; rr++) inv[rr] = 1.f / l_[mi][rr];
#pragma unroll
        for (int nd = 0; nd < 4; nd++)
#pragma unroll
            for (int rr = 0; rr < 4; rr++)
                Qf[base + (size_t)(q0 + w * 32 + mi * 16 + lq * 4 + rr) * 1024 +
                   nd * 16 + lr] = accO[mi][nd][rr] * inv[rr];
    }
}

// ---------------- LayerNorm(qx + att) ----------------------------------------
__global__ __launch_bounds__(256)
void ln_kernel(const float* __restrict__ qx, const float* __restrict__ att,
               const float* __restrict__ w, const float* __restrict__ bch,
               float* __restrict__ zn)
{
    const int row = blockIdx.x, tid = threadIdx.x;
    const size_t off = (size_t)row * 1024 + tid * 4;
    const f32x4 q4 = *(const f32x4*)(qx + off);
    const f32x4 a4 = *(const f32x4*)(att + off);
    float x[4];
#pragma unroll
    for (int i = 0; i < 4; i++) x[i] = q4[i] + a4[i];

    __shared__ float red[8];
    float part = x[0] + x[1] + x[2] + x[3];
#pragma unroll
    for (int d = 1; d < 64; d <<= 1) part += __shfl_xor(part, d);
    if ((tid & 63) == 0) red[tid >> 6] = part;
    __syncthreads();
    const float mu = (red[0] + red[1] + red[2] + red[3]) * (1.f / 1024.f);

    float p2 = 0.f;
#pragma unroll
    for (int i = 0; i < 4; i++) { const float d = x[i] - mu; p2 += d * d; }
#pragma unroll
    for (int d = 1; d < 64; d <<= 1) p2 += __shfl_xor(p2, d);
    if ((tid & 63) == 0) red[4 + (tid >> 6)] = p2;
    __syncthreads();
    const float var  = (red[4] + red[5] + red[6] + red[7]) * (1.f / 1024.f);
    const float rstd = 1.f / sqrtf(var + 1e-5f);

    const f32x4 w4 = *(const f32x4*)(w + tid * 4);
    const f32x4 b4 = *(const f32x4*)(bch + tid * 4);
    f32x4 out;
#pragma unroll
    for (int i = 0; i < 4; i++)
        out[i] = (x[i] - mu) * rstd * w4[i] + b4[i];
    *(f32x4*)(zn + off) = out;
}

// ---------------- router: logits + first-max argmax --------------------------
__global__ __launch_bounds__(64)
void router_kernel(const float* __restrict__ zn, const float* __restrict__ Wsw,
                   const float* __restrict__ bsw, int* __restrict__ routes)
{
    const int t = blockIdx.x, lane = threadIdx.x;
    const float* x = zn + (size_t)t * 1024;
    float acc[16];
#pragma unroll
    for (int e = 0; e < 16; e++) acc[e] = 0.f;
    for (int ii = 0; ii < 16; ii++) {
        const float xv = x[lane + 64 * ii];
#pragma unroll
        for (int e = 0; e < 16; e++)
            acc[e] += xv * Wsw[e * 1024 + lane + 64 * ii];
    }
#pragma unroll
    for (int e = 0; e < 16; e++)
#pragma unroll
        for (int d = 1; d < 64; d <<= 1) acc[e] += __shfl_xor(acc[e], d);
    if (lane == 0) {
        float best = acc[0] + bsw[0];
        int bi = 0;
#pragma unroll
        for (int e = 1; e < 16; e++) {
            const float lg = acc[e] + bsw[e];
            if (lg > best) { best = lg; bi = e; }   // strict > == np first-max
        }
        routes[t] = bi;
    }
}

// ---------------- capacity scan ----------------------------------------------
__global__ __launch_bounds__(1024)
void route_scan(const int* __restrict__ routes, int* __restrict__ slot_of_token,
                int* __restrict__ token_of_slot)
{
    const int wv = threadIdx.x >> 6;      // expert id
    const int lane = threadIdx.x & 63;
    int cnt = 0;
    for (int c = 0; c < NTOK / 64; c++) {
        const int tok = c * 64 + lane;
        const bool match = (routes[tok] == wv);
        const unsigned long long mask = __ballot(match);
        const int pos = cnt + __popcll(mask & ((1ull << lane) - 1ull));
        if (match) {
            if (pos < CAP) {
                slot_of_token[tok] = wv * CAP + pos;
                token_of_slot[wv * CAP + pos] = tok;
            } else slot_of_token[tok] = -1;
        }
        cnt += __popcll(mask);
    }
    const int filled = cnt < CAP ? cnt : CAP;
    for (int s2 = filled + lane; s2 < CAP; s2 += 64)
        token_of_slot[wv * CAP + s2] = -1;
}

// ---------------- expert FFN -------------------------------------------------
__global__ __launch_bounds__(64)
void ffn1(const float* __restrict__ zn, const int* __restrict__ token_of_slot,
          const float* __restrict__ W1, const float* __restrict__ b1,
          float* __restrict__ hbuf)
{
    const int s = blockIdx.x, lane = threadIdx.x;
    const int tok = token_of_slot[s];
    if (tok < 0) return;
    const int e = s >> 8;
    const float* w = W1 + (size_t)e * CC * NHID + lane;
    const float* x = zn + (size_t)tok * 1024;
    float acc = 0.f;
#pragma unroll 8
    for (int i = 0; i < 1024; i++) acc += x[i] * w[(size_t)i * NHID];
    acc += b1[e * NHID + lane];
    hbuf[(size_t)s * NHID + lane] = fmaxf(acc, 0.f);
}

__global__ __launch_bounds__(256)
void ffn2(const float* __restrict__ hbuf, const int* __restrict__ token_of_slot,
          const float* __restrict__ W2, const float* __restrict__ b2,
          float* __restrict__ ybuf)
{
    const int s = blockIdx.x, tid = threadIdx.x;
    const int tok = token_of_slot[s];
    if (tok < 0) return;
    const int e = s >> 8;
    const int c0 = tid * 4;
    const float* w = W2 + (size_t)e * NHID * CC + c0;
    const float* hrow = hbuf + (size_t)s * NHID;
    const f32x4 b4 = *(const f32x4*)(b2 + e * CC + c0);
    float a0 = b4[0], a1 = b4[1], a2 = b4[2], a3 = b4[3];
#pragma unroll 8
    for (int k = 0; k < NHID; k++) {
        const float hv = hrow[k];
        const f32x4 w4 = *(const f32x4*)(w + (size_t)k * CC);
        a0 += hv * w4[0]; a1 += hv * w4[1];
        a2 += hv * w4[2]; a3 += hv * w4[3];
    }
    const f32x4 out = {a0, a1, a2, a3};
    *(f32x4*)(ybuf + (size_t)s * 1024 + c0) = out;
}

// ---------------- final: out = zn + (kept ? y : zn) --------------------------
__global__ __launch_bounds__(256)
void assemble(const float* __restrict__ zn, const float* __restrict__ ybuf,
              const int* __restrict__ slot_of_token, float* __restrict__ out)
{
    const int tok = blockIdx.x, tid = threadIdx.x;
    const int slot = slot_of_token[tok];
    const size_t off = (size_t)tok * 1024 + tid * 4;
    const f32x4 z4 = *(const f32x4*)(zn + off);
    f32x4 m4;
    if (slot >= 0) m4 = *(const f32x4*)(ybuf + (size_t)slot * 1024 + tid * 4);
    else           m4 = z4;
    f32x4 o;
#pragma unroll
    for (int i = 0; i < 4; i++) o[i] = z4[i] + m4[i];
    *(f32x4*)(out + off) = o;
}

__global__ __launch_bounds__(256)
void fill_mask(float* __restrict__ p, int n)
{
    const int i = blockIdx.x * 256 + threadIdx.x;
    if (i < n) p[i] = 1.0f;
}

// ---------------- launch -----------------------------------------------------
extern "C" void kernel_launch(void* const* d_in, const int* in_sizes, int n_in,
                              void* d_out, int out_size, void* d_ws, size_t ws_size,
                              hipStream_t stream)
{
    (void)out_size; (void)ws_size;
    const float* qx = (const float*)d_in[0];
    const float* kx = (const float*)d_in[1];
    const float* vx = (const float*)d_in[2];
    int wbase = 4;
    if (n_in >= 4 && in_sizes[3] != NB * LL) wbase = 3;
    const float* WQ   = (const float*)d_in[wbase + 0];
    const float* bQ   = (const float*)d_in[wbase + 1];
    const float* WK   = (const float*)d_in[wbase + 2];
    const float* bK   = (const float*)d_in[wbase + 3];
    const float* WV   = (const float*)d_in[wbase + 4];
    const float* bV   = (const float*)d_in[wbase + 5];
    const float* WO   = (const float*)d_in[wbase + 6];
    const float* bO   = (const float*)d_in[wbase + 7];
    const float* ln1w = (const float*)d_in[wbase + 8];
    const float* ln1b = (const float*)d_in[wbase + 9];
    const float* Wsw  = (const float*)d_in[wbase + 10];
    const float* bsw  = (const float*)d_in[wbase + 11];
    const float* W1   = (const float*)d_in[wbase + 12];
    const float* b1   = (const float*)d_in[wbase + 13];
    const float* W2   = (const float*)d_in[wbase + 14];
    const float* b2   = (const float*)d_in[wbase + 15];

    char* D   = (char*)d_out;
    char* wsb = (char*)d_ws;

    // Buffer plan (ws proven to 54 MiB; d_out = 96 MiB f32 + mask):
    //   Qbuf(=Z) @ ws0..32 | la2 @ ws32..48 | lw @ ws48..54
    //   la0 @ D0..16 | la1 @ D16..32 | Kbuf @ D32..64 | Vbuf @ D64..96
    float* Qbuf = (float*)(wsb);
    bf16*  la0  = (bf16*)(D);
    bf16*  la1  = (bf16*)(D + (size_t)16 * MB);
    bf16*  la2  = (bf16*)(wsb + (size_t)32 * MB);
    bf16*  lw0  = (bf16*)(wsb + (size_t)48 * MB);
    bf16*  lw1  = (bf16*)(wsb + (size_t)50 * MB);
    bf16*  lw2  = (bf16*)(wsb + (size_t)52 * MB);
    float* Kbuf = (float*)(D + (size_t)32 * MB);
    float* Vbuf = (float*)(D + (size_t)64 * MB);

    const dim3 gblk(NTOK / 128, CC / 128, 1);
    const int GA = NTOK * 1024 / 1024;   // 8192 blocks
    const int GW = CC * 1024 / 1024;     // 1024 blocks

    split3<<<GA, 256, 0, stream>>>(qx, la0, la1, la2);
    split3<<<GW, 256, 0, stream>>>(WQ, lw0, lw1, lw2);
    gemm_limb6<<<gblk, 256, 0, stream>>>(la0, la1, la2, lw0, lw1, lw2, bQ, Qbuf, NTOK, CC, CC);
    split3<<<GA, 256, 0, stream>>>(kx, la0, la1, la2);
    split3<<<GW, 256, 0, stream>>>(WK, lw0, lw1, lw2);
    gemm_limb6<<<gblk, 256, 0, stream>>>(la0, la1, la2, lw0, lw1, lw2, bK, Kbuf, NTOK, CC, CC);
    split3<<<GA, 256, 0, stream>>>(vx, la0, la1, la2);
    split3<<<GW, 256, 0, stream>>>(WV, lw0, lw1, lw2);
    gemm_limb6<<<gblk, 256, 0, stream>>>(la0, la1, la2, lw0, lw1, lw2, bV, Vbuf, NTOK, CC, CC);

    flash_mfma<<<1024, 256, 0, stream>>>(Qbuf, Kbuf, Vbuf);   // Z -> Qbuf in-place

    // out-proj: att = z @ WO^T + bO   (z = Qbuf; la dead -> reuse for z limbs)
    split3<<<GA, 256, 0, stream>>>(Qbuf, la0, la1, la2);
    split3<<<GW, 256, 0, stream>>>(WO, lw0, lw1, lw2);
    float* attbuf = Kbuf;   // Kf32 dead after flash
    gemm_limb6<<<gblk, 256, 0, stream>>>(la0, la1, la2, lw0, lw1, lw2, bO, attbuf, NTOK, CC, CC);

    float* znbuf = Vbuf;    // Vf32 dead after flash
    ln_kernel<<<NTOK, 256, 0, stream>>>(qx, attbuf, ln1w, ln1b, znbuf);

    // MoE scratch (all dead regions post out-proj)
    int*   routes        = (int*)(wsb + (size_t)32 * MB);
    int*   slot_of_token = (int*)(wsb + (size_t)32 * MB + 64 * 1024);
    int*   token_of_slot = (int*)(wsb + (size_t)32 * MB + 128 * 1024);
    float* hbuf          = (float*)(wsb + (size_t)33 * MB);
    float* ybuf          = (float*)(wsb + (size_t)34 * MB);   // 16 MiB -> ws34..50

    router_kernel<<<NTOK, 64, 0, stream>>>(znbuf, Wsw, bsw, routes);
    route_scan<<<1, 1024, 0, stream>>>(routes, slot_of_token, token_of_slot);
    ffn1<<<NE * CAP, 64, 0, stream>>>(znbuf, token_of_slot, W1, b1, hbuf);
    ffn2<<<NE * CAP, 256, 0, stream>>>(hbuf, token_of_slot, W2, b2, ybuf);

    assemble<<<NTOK, 256, 0, stream>>>(znbuf, ybuf, slot_of_token, (float*)d_out);

    // passthrough outputs (overwrite dead attbuf/znbuf regions), mask = 1.0f
    hipMemcpyAsync(D + (size_t)32 * MB, (const void*)kx,
                   (size_t)NTOK * 1024 * 4, hipMemcpyDeviceToDevice, stream);
    hipMemcpyAsync(D + (size_t)64 * MB, (const void*)vx,
                   (size_t)NTOK * 1024 * 4, hipMemcpyDeviceToDevice, stream);
    fill_mask<<<NTOK / 256, 256, 0, stream>>>((float*)d_out + (size_t)3 * NTOK * 1024, NTOK);
}